// Round 5
// baseline (301.133 us; speedup 1.0000x reference)
//
#include <hip/hip_runtime.h>

// Problem constants
#define B_   32
#define H_   64
#define W_   64
#define CIN  128
#define F_   256
#define K_   1152          // 3*3*128
#define M_   4096          // H*W per batch

// Padded bf16 image: [B][66][66][128]
#define HP_   66
#define XPROW (66*128)          // 8448
#define XPIMG (66*66*128)       // 557568
#define XP_ELEMS ((size_t)B_ * XPIMG)
#define XP_BYTES (XP_ELEMS * 2)                 // 35,684,352

#define WBT_BYTES ((size_t)B_ * F_ * K_ * 2)    // 18,874,368
#define FULL_WS   (WBT_BYTES + XP_BYTES + 256)
#define ZPAGE_OFF WBT_BYTES                     // mid-tier zero page

// gemm256 geometry
#define BM_ 256
#define BK_ 64

typedef __attribute__((ext_vector_type(8))) short bf16x8;
typedef __attribute__((ext_vector_type(4))) float f32x4;

// pack two floats -> two bf16 (round-to-nearest) in one v_perm
__device__ __forceinline__ unsigned pkbf(float a, float b) {
    unsigned ua = __builtin_bit_cast(unsigned, a) + 0x8000u;
    unsigned ub = __builtin_bit_cast(unsigned, b) + 0x8000u;
    return __builtin_amdgcn_perm(ub, ua, 0x07060302u);
}

__device__ __forceinline__ void async16(const void* g, void* l) {
    __builtin_amdgcn_global_load_lds(
        (const __attribute__((address_space(1))) unsigned int*)g,
        (__attribute__((address_space(3))) unsigned int*)l, 16, 0, 0);
}

#define PHB do { __builtin_amdgcn_s_barrier(); \
                 __builtin_amdgcn_sched_barrier(0); } while (0)

// ---------------------------------------------------------------------------
// Fused preprocessing: blocks [0,4608) do WbT, blocks [4608,13320) do Xp.
//   WbT[b][f][k] = bf16( W[k][f] * Werr[b][k][f] )
//   Xp = bf16 zero-padded X image [32][66][66][128]
// ---------------------------------------------------------------------------
__global__ void prep_kernel(const float* __restrict__ W,
                            const float* __restrict__ Werr,
                            const float* __restrict__ X,
                            unsigned short* __restrict__ WbT,
                            unsigned short* __restrict__ Xp,
                            unsigned int* __restrict__ zpage) {
    __shared__ float tile[32 * 68];
    int bid = blockIdx.x;
    int t   = threadIdx.x;

    if (bid < 4608) {
        // ---- WbT body ----
        int ft   = bid & 3;
        int rest = bid >> 2;
        int kt   = rest % 36;
        int b    = rest / 36;
        int k0 = kt * 32;
        int f0 = ft * 64;

        if (bid == 0 && t < 64) zpage[t] = 0u;   // mid-tier zero page

        #pragma unroll
        for (int i = 0; i < 2; ++i) {
            int c   = i * 256 + t;        // 0..511
            int kl  = c >> 4;             // 0..31
            int fl4 = c & 15;             // f offset = fl4*4
            size_t src = (size_t)(k0 + kl) * F_ + f0 + fl4 * 4;
            f32x4 w4 = *(const f32x4*)&W[src];
            f32x4 e4 = *(const f32x4*)&Werr[(size_t)b * (K_ * F_) + src];
            f32x4 v  = w4 * e4;
            *(f32x4*)&tile[kl * 68 + fl4 * 4] = v;
        }
        __syncthreads();
        {
            int c  = t;
            int fl = c >> 2;              // 0..63
            int ku = c & 3;               // k unit of 8
            unsigned pk[4];
            #pragma unroll
            for (int j2 = 0; j2 < 4; ++j2) {
                float x0 = tile[(ku * 8 + j2 * 2 + 0) * 68 + fl];
                float x1 = tile[(ku * 8 + j2 * 2 + 1) * 68 + fl];
                pk[j2] = pkbf(x0, x1);
            }
            size_t dst = ((size_t)(b * F_ + f0 + fl)) * K_ + k0 + ku * 8;
            *(uint4*)&WbT[dst] = make_uint4(pk[0], pk[1], pk[2], pk[3]);
        }
    } else {
        // ---- Xp body ----
        int e = (bid - 4608) * 256 + t;   // chunk id, < 2,230,272
        int c16  = e & 15;                // channel block of 8
        int pos  = e >> 4;                // (b*66 + hp)*66 + wp
        int wp   = pos % 66;
        int rest = pos / 66;
        int hp   = rest % 66;
        int b    = rest / 66;
        uint4 out;
        if (hp >= 1 && hp <= 64 && wp >= 1 && wp <= 64) {
            const float* src = X + (((size_t)b * 64 + (hp - 1)) * 64 + (wp - 1)) * 128
                                 + c16 * 8;
            f32x4 a = *(const f32x4*)src;
            f32x4 c = *(const f32x4*)(src + 4);
            out.x = pkbf(a[0], a[1]);  out.y = pkbf(a[2], a[3]);
            out.z = pkbf(c[0], c[1]);  out.w = pkbf(c[2], c[3]);
        } else {
            out = make_uint4(0u, 0u, 0u, 0u);
        }
        *(uint4*)&Xp[(size_t)e * 8] = out;
    }
}

// Standalone WbT kernel for the mid-tier path (no Xp space in ws).
__global__ void wbt_kernel(const float* __restrict__ W,
                           const float* __restrict__ Werr,
                           unsigned short* __restrict__ WbT,
                           unsigned int* __restrict__ zpage) {
    __shared__ float tile[32 * 68];
    int bid = blockIdx.x;
    int ft   = bid & 3;
    int rest = bid >> 2;
    int kt   = rest % 36;
    int b    = rest / 36;
    int k0 = kt * 32;
    int f0 = ft * 64;
    int t  = threadIdx.x;

    if (bid == 0 && t < 64) zpage[t] = 0u;

    #pragma unroll
    for (int i = 0; i < 2; ++i) {
        int c   = i * 256 + t;
        int kl  = c >> 4;
        int fl4 = c & 15;
        size_t src = (size_t)(k0 + kl) * F_ + f0 + fl4 * 4;
        f32x4 w4 = *(const f32x4*)&W[src];
        f32x4 e4 = *(const f32x4*)&Werr[(size_t)b * (K_ * F_) + src];
        f32x4 v  = w4 * e4;
        *(f32x4*)&tile[kl * 68 + fl4 * 4] = v;
    }
    __syncthreads();
    {
        int c  = t;
        int fl = c >> 2;
        int ku = c & 3;
        unsigned pk[4];
        #pragma unroll
        for (int j2 = 0; j2 < 4; ++j2) {
            float x0 = tile[(ku * 8 + j2 * 2 + 0) * 68 + fl];
            float x1 = tile[(ku * 8 + j2 * 2 + 1) * 68 + fl];
            pk[j2] = pkbf(x0, x1);
        }
        size_t dst = ((size_t)(b * F_ + f0 + fl)) * K_ + k0 + ku * 8;
        *(uint4*)&WbT[dst] = make_uint4(pk[0], pk[1], pk[2], pk[3]);
    }
}

// ---------------------------------------------------------------------------
// gemm256 v4: faithful m201 8-phase port. 256x256 tile, BK=64, 8 waves.
// Iteration = 2 K-tiles (e=2p in buf0, o=2p+1 in buf1), 8 phases; each
// phase: {ds_read one quadrant's frags | stage ONE 16KB half-tile (2
// gload_lds/thr) | barrier | setprio 16 MFMA | [counted gate] | barrier}.
// Stage schedule (1 half/phase, uniform):
//   ph1:B(o)hi ph2:A(o)lo ph3:A(o)hi ph4:B(e+2)lo ph5:B(e+2)hi
//   ph6:A(e+2)lo ph7:A(e+2)hi ph8:B(o+2)lo      [B(o)lo staged ph8(p-1)]
// Gates (per-wave queue ledger, oldest->newest; 2 instrs per half):
//   end-ph1: [Aeh,Bol,Boh]=6        -> vmcnt(4) drains Aeh   (ph2 reads Ae-hi)
//   end-ph4: [Bol,Boh,Aol,Aoh,Bel']=10 -> vmcnt(4) drains B(o)+A(o)lo (ph5)
//   end-ph5: [Aoh,Bel',Beh']=6      -> vmcnt(4) drains Aoh   (ph6 reads Ao-hi)
//   end-ph8: [Bel',Beh',Ael',Aeh',Bol'']=10 -> vmcnt(4)      (next ph1)
//   invariant at ph1 entry: [Ae-hi, B(o)lo] outstanding. Never vmcnt(0)
//   mid-loop; last pair degrades gates to 2/0 (pf guards).
// WAR: every stage targets a half whose last ds_read is >=1 barrier before
// the issue point (B:ph3/ph7; A-lo:ph3/ph7; A-hi:ph4/ph8). Swizzle formulas
// identical to verified v3 (0 bank conflicts, refcheck'd).
// grid = 512, XCD-swizzled.
// ---------------------------------------------------------------------------
__global__ __launch_bounds__(512, 2)
void gemm256_kernel(const unsigned short* __restrict__ Xp,
                    const unsigned short* __restrict__ WbT,
                    const float* __restrict__ bias,
                    const float* __restrict__ Berr,
                    float* __restrict__ Out) {
    __shared__ unsigned short As[2][BM_ * BK_];   // 2 x 32KB
    __shared__ unsigned short Bs[2][BM_ * BK_];   // 2 x 32KB

    int bid = blockIdx.x;
    int g   = (bid & 7) * 64 + (bid >> 3);   // bijective, 512 % 8 == 0
    int b   = g >> 4;                        // 0..31
    int mt  = g & 15;                        // 0..15
    int pm0 = mt * 256;

    int t    = threadIdx.x;
    int lane = t & 63;
    int wv   = t >> 6;
    int wm   = wv >> 2;       // 0..1
    int wn   = wv & 3;        // 0..3
    int l16  = lane & 15;
    int quad = lane >> 4;
    int swz  = (l16 & 7) << 4;   // byte-XOR for ds_read (bits 4-6)

    const unsigned short* XpB = Xp + (size_t)b * XPIMG;
    const unsigned short* WbB = WbT + (size_t)b * F_ * K_;

    // staging: half h (rows h*128..h*128+127), 2 chunks/thread (c=t, t+512).
    // LDS dest linear (wave-uniform base + lane*16); source chunk
    // inverse-swizzled: sc = (c&7) ^ (row&7).
    int asrc[2][2], bsrc[2][2];
    #pragma unroll
    for (int cc = 0; cc < 2; ++cc) {
        int c   = t + cc * 512;
        int r16 = c >> 3;             // 0..127
        int col = c & 7;
        #pragma unroll
        for (int h = 0; h < 2; ++h) {
            int row = h * 128 + r16;  // 0..255
            int sc  = col ^ (row & 7);
            asrc[h][cc] = (mt * 4 + (row >> 6)) * XPROW + (row & 63) * 128 + sc * 8;
            bsrc[h][cc] = row * K_ + sc * 8;
        }
    }

    f32x4 acc[8][4];
    #pragma unroll
    for (int mi = 0; mi < 8; ++mi)
        #pragma unroll
        for (int ni = 0; ni < 4; ++ni)
            acc[mi][ni] = (f32x4){0.f, 0.f, 0.f, 0.f};

    auto stA = [&](int buf, int h, int ko) {
        async16(XpB + asrc[h][0] + ko, &As[buf][h * 8192 + t * 8]);
        async16(XpB + asrc[h][1] + ko, &As[buf][h * 8192 + 4096 + t * 8]);
    };
    auto stB = [&](int buf, int h, int ko) {
        async16(WbB + bsrc[h][0] + ko, &Bs[buf][h * 8192 + t * 8]);
        async16(WbB + bsrc[h][1] + ko, &Bs[buf][h * 8192 + 4096 + t * 8]);
    };
    auto rdB = [&](bf16x8* dst, const unsigned short* Bc, int ks) {
        #pragma unroll
        for (int ni = 0; ni < 4; ++ni) {
            int row = wn * 64 + ni * 16 + l16;
            dst[ni] = *(const bf16x8*)((const char*)Bc +
                       ((row * 128 + quad * 16 + ks * 64) ^ swz));
        }
    };
    auto rdA = [&](bf16x8* dst, const unsigned short* Ac, int qm, int ks) {
        #pragma unroll
        for (int mi = 0; mi < 4; ++mi) {
            int row = wm * 128 + qm * 64 + mi * 16 + l16;
            dst[mi] = *(const bf16x8*)((const char*)Ac +
                       ((row * 128 + quad * 16 + ks * 64) ^ swz));
        }
    };
    auto mm = [&](int qm, const bf16x8* a, const bf16x8* bb) {
        __builtin_amdgcn_s_setprio(1);
        #pragma unroll
        for (int mi = 0; mi < 4; ++mi)
            #pragma unroll
            for (int ni = 0; ni < 4; ++ni)
                acc[qm * 4 + mi][ni] = __builtin_amdgcn_mfma_f32_16x16x32_bf16(
                    a[mi], bb[ni], acc[qm * 4 + mi][ni], 0, 0, 0);
        __builtin_amdgcn_s_setprio(0);
    };

    // ---- prologue: tile0 -> buf0 (B-lo,B-hi,A-lo,A-hi), tile1 B-lo -> buf1
    stB(0, 0, 0); stB(0, 1, 0); stA(0, 0, 0); stA(0, 1, 0); stB(1, 0, 64);
    asm volatile("s_waitcnt vmcnt(4)" ::: "memory");   // drain B0l,B0h,A0l
    PHB;

    for (int p = 0; p < 9; ++p) {
        const bool pf = (p < 8);
        // tile o = 2p+1 (khw=p); tile e2 = 2p+2 (khw=p+1); tile o2 = 2p+3
        int kh_o = (p * 11) >> 5;
        int kw_o = p - 3 * kh_o;
        int koA_o = kh_o * XPROW + kw_o * 128 + 64;
        int koB_o = (2 * p + 1) * 64;
        int q1 = p + 1;
        int kh_e = (q1 * 11) >> 5;
        int kw_e = q1 - 3 * kh_e;
        int koA_e2 = kh_e * XPROW + kw_e * 128;
        int koB_e2 = (2 * p + 2) * 64;
        int koB_o2 = (2 * p + 3) * 64;

        const unsigned short* A0 = As[0]; const unsigned short* B0 = Bs[0];
        const unsigned short* A1 = As[1]; const unsigned short* B1 = Bs[1];

        bf16x8 bb[4], aa[4];

        // ===== ph1: tile e, ks0, qm0 =====
        rdB(bb, B0, 0); rdA(aa, A0, 0, 0);
        stB(1, 1, koB_o);
        PHB;
        mm(0, aa, bb);
        asm volatile("s_waitcnt vmcnt(4)" ::: "memory");
        PHB;
        // ===== ph2: tile e, ks0, qm1 =====
        rdA(aa, A0, 1, 0);
        stA(1, 0, koA_o);
        PHB;
        mm(1, aa, bb);
        PHB;
        // ===== ph3: tile e, ks1, qm0 =====
        rdB(bb, B0, 1); rdA(aa, A0, 0, 1);
        stA(1, 1, koA_o);
        PHB;
        mm(0, aa, bb);
        PHB;
        // ===== ph4: tile e, ks1, qm1 =====
        rdA(aa, A0, 1, 1);
        if (pf) stB(0, 0, koB_e2);
        PHB;
        mm(1, aa, bb);
        if (pf) asm volatile("s_waitcnt vmcnt(4)" ::: "memory");
        else    asm volatile("s_waitcnt vmcnt(2)" ::: "memory");
        PHB;
        // ===== ph5: tile o, ks0, qm0 =====
        rdB(bb, B1, 0); rdA(aa, A1, 0, 0);
        if (pf) stB(0, 1, koB_e2);
        PHB;
        mm(0, aa, bb);
        if (pf) asm volatile("s_waitcnt vmcnt(4)" ::: "memory");
        else    asm volatile("s_waitcnt vmcnt(0)" ::: "memory");
        PHB;
        // ===== ph6: tile o, ks0, qm1 =====
        rdA(aa, A1, 1, 0);
        if (pf) stA(0, 0, koA_e2);
        PHB;
        mm(1, aa, bb);
        PHB;
        // ===== ph7: tile o, ks1, qm0 =====
        rdB(bb, B1, 1); rdA(aa, A1, 0, 1);
        if (pf) stA(0, 1, koA_e2);
        PHB;
        mm(0, aa, bb);
        PHB;
        // ===== ph8: tile o, ks1, qm1 =====
        rdA(aa, A1, 1, 1);
        if (pf) stB(1, 0, koB_o2);
        PHB;
        mm(1, aa, bb);
        if (pf) asm volatile("s_waitcnt vmcnt(4)" ::: "memory");
        PHB;
    }

    // ---- epilogue: + bias*Berr, ReLU, store fp32 ----
    float mb[4];
    #pragma unroll
    for (int ni = 0; ni < 4; ++ni) {
        int f = wn * 64 + ni * 16 + l16;
        mb[ni] = bias[f] * Berr[b * F_ + f];
    }
    #pragma unroll
    for (int mi = 0; mi < 8; ++mi) {
        #pragma unroll
        for (int rr = 0; rr < 4; ++rr) {
            int mm2 = pm0 + wm * 128 + mi * 16 + quad * 4 + rr;
            float* orow = Out + ((size_t)b * M_ + mm2) * F_ + wn * 64;
            #pragma unroll
            for (int ni = 0; ni < 4; ++ni) {
                float v = acc[mi][ni][rr] + mb[ni];
                orow[ni * 16 + l16] = fmaxf(v, 0.0f);
            }
        }
    }
}

// ---------------------------------------------------------------------------
// Mid-tier path (verified): fp32 X + in-loop cvt, 128x128 tile.
// ---------------------------------------------------------------------------
__global__ __launch_bounds__(256, 2)
void gemm_kernel_f32(const float* __restrict__ X,
                     const unsigned short* __restrict__ WbT,
                     const float* __restrict__ zpage,
                     const float* __restrict__ bias,
                     const float* __restrict__ Berr,
                     float* __restrict__ Out) {
    __shared__ unsigned short As[128 * 32];
    __shared__ unsigned short Bs[128 * 32];

    int bid = blockIdx.x;
    int g   = (bid & 7) | ((bid >> 8) << 3);
    int mt  = (bid >> 3) & 31;
    int b   = g >> 1;
    int nt  = g & 1;
    int pm0 = mt * 128;

    int t    = threadIdx.x;
    int lane = t & 63;
    int wv   = t >> 6;
    int wm   = wv >> 1;
    int wn   = wv & 1;
    int l16  = lane & 15;
    int quad = lane >> 4;

    int ml   = t >> 1;
    int half = t & 1;
    int m    = pm0 + ml;
    int hb   = m >> 6;
    int wwv  = m & 63;
    const float* Abase = X + (((size_t)b * 64 + hb - 1) * 64 + (wwv - 1)) * 128
                           + half * 16;
    unsigned vm = 0;
    #pragma unroll
    for (int khw = 0; khw < 9; ++khw) {
        int kh = (khw * 11) >> 5;
        int kw = khw - kh * 3;
        bool ok = ((unsigned)(hb + kh - 1) < 64u) && ((unsigned)(wwv + kw - 1) < 64u);
        vm |= (unsigned)ok << khw;
    }
    int ldsA = ml * 32 + half * 16;

    const unsigned short* wb = WbT + ((size_t)(b * F_ + nt * 128)) * K_;
    const unsigned short* Bbase[2];
    int ldsB[2];
    #pragma unroll
    for (int cc = 0; cc < 2; ++cc) {
        int c   = t + cc * 256;
        int nl  = c >> 2;
        int off = c & 3;
        Bbase[cc] = wb + (size_t)nl * K_ + off * 8;
        ldsB[cc]  = c * 8;
    }

    f32x4 acc[4][4];
    #pragma unroll
    for (int mi = 0; mi < 4; ++mi)
        #pragma unroll
        for (int ni = 0; ni < 4; ++ni)
            acc[mi][ni] = (f32x4){0.f, 0.f, 0.f, 0.f};

    f32x4 pr0, pr1, pr2, pr3;
    {
        const float* p = (vm & 1) ? Abase : zpage;
        pr0 = *(const f32x4*)(p);
        pr1 = *(const f32x4*)(p + 4);
        pr2 = *(const f32x4*)(p + 8);
        pr3 = *(const f32x4*)(p + 12);
    }

    for (int kt = 0; kt < 36; ++kt) {
        uint4 lo, hi;
        lo.x = pkbf(pr0[0], pr0[1]);  lo.y = pkbf(pr0[2], pr0[3]);
        lo.z = pkbf(pr1[0], pr1[1]);  lo.w = pkbf(pr1[2], pr1[3]);
        hi.x = pkbf(pr2[0], pr2[1]);  hi.y = pkbf(pr2[2], pr2[3]);
        hi.z = pkbf(pr3[0], pr3[1]);  hi.w = pkbf(pr3[2], pr3[3]);

        if (kt) __syncthreads();
        *(uint4*)&As[ldsA]     = lo;
        *(uint4*)&As[ldsA + 8] = hi;
        #pragma unroll
        for (int cc = 0; cc < 2; ++cc)
            async16(Bbase[cc] + kt * 32, &Bs[ldsB[cc]]);
        __syncthreads();

        if (kt < 35) {
            int ktn  = kt + 1;
            int khw  = ktn >> 2;
            int kh   = (khw * 11) >> 5;
            int kw   = khw - kh * 3;
            int koff = kh * 8192 + kw * 128 + ((ktn & 3) << 5);
            const float* p = ((vm >> khw) & 1) ? Abase + koff : zpage;
            pr0 = *(const f32x4*)(p);
            pr1 = *(const f32x4*)(p + 4);
            pr2 = *(const f32x4*)(p + 8);
            pr3 = *(const f32x4*)(p + 12);
        }

        bf16x8 af[4], bf[4];
        #pragma unroll
        for (int i = 0; i < 4; ++i) {
            af[i] = *(const bf16x8*)&As[(wm * 64 + i * 16 + l16) * 32 + quad * 8];
            bf[i] = *(const bf16x8*)&Bs[(wn * 64 + i * 16 + l16) * 32 + quad * 8];
        }
        #pragma unroll
        for (int mi = 0; mi < 4; ++mi)
            #pragma unroll
            for (int ni = 0; ni < 4; ++ni)
                acc[mi][ni] = __builtin_amdgcn_mfma_f32_16x16x32_bf16(
                    af[mi], bf[ni], acc[mi][ni], 0, 0, 0);
    }

    float mb[4];
    #pragma unroll
    for (int ni = 0; ni < 4; ++ni) {
        int f = nt * 128 + wn * 64 + ni * 16 + l16;
        mb[ni] = bias[f] * Berr[b * F_ + f];
    }
    #pragma unroll
    for (int mi = 0; mi < 4; ++mi) {
        #pragma unroll
        for (int rr = 0; rr < 4; ++rr) {
            int mm = pm0 + wm * 64 + mi * 16 + quad * 4 + rr;
            float* orow = Out + ((size_t)b * M_ + mm) * F_ + nt * 128 + wn * 64;
            #pragma unroll
            for (int ni = 0; ni < 4; ++ni) {
                float v = acc[mi][ni][rr] + mb[ni];
                orow[ni * 16 + l16] = fmaxf(v, 0.0f);
            }
        }
    }
}

// ---------------------------------------------------------------------------
// Zero-workspace fallback: direct conv (slow but correct), ws < 19MB only.
// ---------------------------------------------------------------------------
__global__ __launch_bounds__(256)
void fallback_kernel(const float* __restrict__ X, const float* __restrict__ W,
                     const float* __restrict__ bias, const float* __restrict__ Werr,
                     const float* __restrict__ Berr, float* __restrict__ Out) {
    __shared__ float Xs[3 * 66 * 128];
    int bid = blockIdx.x;
    int b = bid >> 6;
    int h = bid & 63;
    int t = threadIdx.x;
    int f = t;

    for (int e = t; e < 3 * 66 * 128; e += 256) {
        int kh  = e / (66 * 128);
        int rem = e - kh * 66 * 128;
        int w66 = rem >> 7;
        int c   = rem & 127;
        int hh = h + kh - 1, ww = w66 - 1;
        float v = 0.f;
        if (hh >= 0 && hh < 64 && ww >= 0 && ww < 64)
            v = X[(((size_t)b * 64 + hh) * 64 + ww) * 128 + c];
        Xs[e] = v;
    }
    __syncthreads();

    float acc[64];
    #pragma unroll
    for (int w = 0; w < 64; ++w) acc[w] = 0.f;

    for (int kk = 0; kk < 9; ++kk) {
        int kh = (kk * 11) >> 5;
        int kw = kk - kh * 3;
        for (int c = 0; c < 128; ++c) {
            size_t wi = ((size_t)kk * 128 + c) * 256 + f;
            float wvv = W[wi] * Werr[(size_t)b * (K_ * F_) + wi];
            const float* xr = &Xs[(kh * 66 + kw) * 128 + c];
            #pragma unroll
            for (int w = 0; w < 64; ++w)
                acc[w] = fmaf(xr[w * 128], wvv, acc[w]);
        }
    }
    float mb = bias[f] * Berr[b * 256 + f];
    for (int w = 0; w < 64; ++w)
        Out[(((size_t)b * 64 + h) * 64 + w) * 256 + f] = fmaxf(acc[w] + mb, 0.f);
}

// ---------------------------------------------------------------------------
extern "C" void kernel_launch(void* const* d_in, const int* in_sizes, int n_in,
                              void* d_out, int out_size, void* d_ws, size_t ws_size,
                              hipStream_t stream) {
    const float* X    = (const float*)d_in[0];
    const float* W    = (const float*)d_in[1];
    const float* bias = (const float*)d_in[2];
    const float* Werr = (const float*)d_in[3];
    const float* Berr = (const float*)d_in[4];
    float* Out = (float*)d_out;

    if (ws_size >= FULL_WS) {
        unsigned short* WbT = (unsigned short*)d_ws;
        unsigned short* Xp  = (unsigned short*)((char*)d_ws + WBT_BYTES);
        unsigned int*   zpg = (unsigned int*)((char*)d_ws + WBT_BYTES + XP_BYTES);
        prep_kernel<<<4608 + 8712, 256, 0, stream>>>(W, Werr, X, WbT, Xp, zpg);
        gemm256_kernel<<<512, 512, 0, stream>>>(Xp, WbT, bias, Berr, Out);
    } else if (ws_size >= WBT_BYTES + 256) {
        unsigned short* WbT  = (unsigned short*)d_ws;
        unsigned int*   zpg  = (unsigned int*)((char*)d_ws + ZPAGE_OFF);
        wbt_kernel<<<B_ * 36 * 4, 256, 0, stream>>>(W, Werr, WbT, zpg);
        gemm_kernel_f32<<<B_ * 32 * 2, 256, 0, stream>>>(X, WbT, (const float*)zpg,
                                                         bias, Berr, Out);
    } else {
        fallback_kernel<<<B_ * 64, 256, 0, stream>>>(X, W, bias, Werr, Berr, Out);
    }
}

// Round 6
// 297.097 us; speedup vs baseline: 1.0136x; 1.0136x over previous
//
#include <hip/hip_runtime.h>

// Problem constants
#define B_   32
#define H_   64
#define W_   64
#define CIN  128
#define F_   256
#define K_   1152          // 3*3*128
#define M_   4096          // H*W per batch

// Padded bf16 image: [B][66][66][128]
#define HP_   66
#define XPROW (66*128)          // 8448
#define XPIMG (66*66*128)       // 557568
#define XP_ELEMS ((size_t)B_ * XPIMG)
#define XP_BYTES (XP_ELEMS * 2)                 // 35,684,352

#define WBT_BYTES ((size_t)B_ * F_ * K_ * 2)    // 18,874,368
#define FULL_WS   (WBT_BYTES + XP_BYTES + 256)
#define ZPAGE_OFF WBT_BYTES                     // mid-tier zero page

typedef __attribute__((ext_vector_type(8))) short bf16x8;
typedef __attribute__((ext_vector_type(4))) float f32x4;

// pack two floats -> two bf16 (round-to-nearest) in one v_perm
__device__ __forceinline__ unsigned pkbf(float a, float b) {
    unsigned ua = __builtin_bit_cast(unsigned, a) + 0x8000u;
    unsigned ub = __builtin_bit_cast(unsigned, b) + 0x8000u;
    return __builtin_amdgcn_perm(ub, ua, 0x07060302u);
}

__device__ __forceinline__ void async16(const void* g, void* l) {
    __builtin_amdgcn_global_load_lds(
        (const __attribute__((address_space(1))) unsigned int*)g,
        (__attribute__((address_space(3))) unsigned int*)l, 16, 0, 0);
}

#define PHB do { __builtin_amdgcn_s_barrier(); \
                 __builtin_amdgcn_sched_barrier(0); } while (0)

// ---------------------------------------------------------------------------
// Fused preprocessing: blocks [0,4608) do WbT, blocks [4608,13320) do Xp.
//   WbT[b][f][k] = bf16( W[k][f] * Werr[b][k][f] )
//   Xp = bf16 zero-padded X image [32][66][66][128]
// ---------------------------------------------------------------------------
__global__ void prep_kernel(const float* __restrict__ W,
                            const float* __restrict__ Werr,
                            const float* __restrict__ X,
                            unsigned short* __restrict__ WbT,
                            unsigned short* __restrict__ Xp,
                            unsigned int* __restrict__ zpage) {
    __shared__ float tile[32 * 68];
    int bid = blockIdx.x;
    int t   = threadIdx.x;

    if (bid < 4608) {
        // ---- WbT body ----
        int ft   = bid & 3;
        int rest = bid >> 2;
        int kt   = rest % 36;
        int b    = rest / 36;
        int k0 = kt * 32;
        int f0 = ft * 64;

        if (bid == 0 && t < 64) zpage[t] = 0u;   // mid-tier zero page

        #pragma unroll
        for (int i = 0; i < 2; ++i) {
            int c   = i * 256 + t;        // 0..511
            int kl  = c >> 4;             // 0..31
            int fl4 = c & 15;             // f offset = fl4*4
            size_t src = (size_t)(k0 + kl) * F_ + f0 + fl4 * 4;
            f32x4 w4 = *(const f32x4*)&W[src];
            f32x4 e4 = *(const f32x4*)&Werr[(size_t)b * (K_ * F_) + src];
            f32x4 v  = w4 * e4;
            *(f32x4*)&tile[kl * 68 + fl4 * 4] = v;
        }
        __syncthreads();
        {
            int c  = t;
            int fl = c >> 2;              // 0..63
            int ku = c & 3;               // k unit of 8
            unsigned pk[4];
            #pragma unroll
            for (int j2 = 0; j2 < 4; ++j2) {
                float x0 = tile[(ku * 8 + j2 * 2 + 0) * 68 + fl];
                float x1 = tile[(ku * 8 + j2 * 2 + 1) * 68 + fl];
                pk[j2] = pkbf(x0, x1);
            }
            size_t dst = ((size_t)(b * F_ + f0 + fl)) * K_ + k0 + ku * 8;
            *(uint4*)&WbT[dst] = make_uint4(pk[0], pk[1], pk[2], pk[3]);
        }
    } else {
        // ---- Xp body ----
        int e = (bid - 4608) * 256 + t;   // chunk id, < 2,230,272
        int c16  = e & 15;                // channel block of 8
        int pos  = e >> 4;                // (b*66 + hp)*66 + wp
        int wp   = pos % 66;
        int rest = pos / 66;
        int hp   = rest % 66;
        int b    = rest / 66;
        uint4 out;
        if (hp >= 1 && hp <= 64 && wp >= 1 && wp <= 64) {
            const float* src = X + (((size_t)b * 64 + (hp - 1)) * 64 + (wp - 1)) * 128
                                 + c16 * 8;
            f32x4 a = *(const f32x4*)src;
            f32x4 c = *(const f32x4*)(src + 4);
            out.x = pkbf(a[0], a[1]);  out.y = pkbf(a[2], a[3]);
            out.z = pkbf(c[0], c[1]);  out.w = pkbf(c[2], c[3]);
        } else {
            out = make_uint4(0u, 0u, 0u, 0u);
        }
        *(uint4*)&Xp[(size_t)e * 8] = out;
    }
}

// Standalone WbT kernel for the mid-tier path (no Xp space in ws).
__global__ void wbt_kernel(const float* __restrict__ W,
                           const float* __restrict__ Werr,
                           unsigned short* __restrict__ WbT,
                           unsigned int* __restrict__ zpage) {
    __shared__ float tile[32 * 68];
    int bid = blockIdx.x;
    int ft   = bid & 3;
    int rest = bid >> 2;
    int kt   = rest % 36;
    int b    = rest / 36;
    int k0 = kt * 32;
    int f0 = ft * 64;
    int t  = threadIdx.x;

    if (bid == 0 && t < 64) zpage[t] = 0u;

    #pragma unroll
    for (int i = 0; i < 2; ++i) {
        int c   = i * 256 + t;
        int kl  = c >> 4;
        int fl4 = c & 15;
        size_t src = (size_t)(k0 + kl) * F_ + f0 + fl4 * 4;
        f32x4 w4 = *(const f32x4*)&W[src];
        f32x4 e4 = *(const f32x4*)&Werr[(size_t)b * (K_ * F_) + src];
        f32x4 v  = w4 * e4;
        *(f32x4*)&tile[kl * 68 + fl4 * 4] = v;
    }
    __syncthreads();
    {
        int c  = t;
        int fl = c >> 2;
        int ku = c & 3;
        unsigned pk[4];
        #pragma unroll
        for (int j2 = 0; j2 < 4; ++j2) {
            float x0 = tile[(ku * 8 + j2 * 2 + 0) * 68 + fl];
            float x1 = tile[(ku * 8 + j2 * 2 + 1) * 68 + fl];
            pk[j2] = pkbf(x0, x1);
        }
        size_t dst = ((size_t)(b * F_ + f0 + fl)) * K_ + k0 + ku * 8;
        *(uint4*)&WbT[dst] = make_uint4(pk[0], pk[1], pk[2], pk[3]);
    }
}

// ---------------------------------------------------------------------------
// gemm v5: 128(M) x 256(N=F) tile, BK=32, 8 waves (2M x 4N), 512 thr.
// LDS 72KB triple-buffered: A 3 x [128 rows][32 shorts] (8KB), B 3 x
// [256][32] (16KB)  ->  2 blocks/CU. Gate stalls of one block are covered
// by the other block's MFMAs (m114 cross-block overlap) — no fine phase
// schedule needed (R3/R5 showed added barriers regress at 1 block/CU).
// Per K-tile kt: { 8 ds_read_b128 (cur) | issue 3 global_load_lds for
// tile kt+2 into buf[(kt+2)%3] | 16 MFMA | vmcnt(3) | barrier }.
// Ledger (3 load-instrs/wave/tile): entry of kt: kt visible, kt+1 in
// flight (3). After issuing kt+2: outstanding 6. vmcnt(3) drains kt+1
// (issued one full tile ago ~ full-tile latency cover), leaves kt+2.
// Never vmcnt(0) mid-loop (only at kt=34 to drain tile 35).
// WAR: buf[(kt+2)%3] == buf[(kt-1)%3]; its readers ran in iter kt-1 and
// their ds_reads were consumed by MFMAs before iter kt-1's barrier.
// Swizzle (64B rows): source chunk sc = col ^ ((row>>1)&3); read slot
// quad ^ ((l16>>1)&3)  ->  16 rows hit 8 distinct 16B slots = 2 lanes/bank
// (free, m136). grid = 1024, XCD-swizzled, exactly 2 resident rounds.
// ---------------------------------------------------------------------------
__global__ __launch_bounds__(512, 4)
void gemm128_kernel(const unsigned short* __restrict__ Xp,
                    const unsigned short* __restrict__ WbT,
                    const float* __restrict__ bias,
                    const float* __restrict__ Berr,
                    float* __restrict__ Out) {
    __shared__ unsigned short As[3][128 * 32];   // 3 x 8KB
    __shared__ unsigned short Bs[3][256 * 32];   // 3 x 16KB

    int bid = blockIdx.x;
    int g   = (bid & 7) * 128 + (bid >> 3);  // bijective, 1024 % 8 == 0
    int b   = g >> 5;                        // 0..31
    int mt  = g & 31;                        // 0..31
    int pm0 = mt * 128;

    int t    = threadIdx.x;
    int lane = t & 63;
    int wv   = t >> 6;
    int wm   = wv >> 2;       // 0..1  (M half: rows wm*64..+63)
    int wn   = wv & 3;        // 0..3  (N quarter: cols wn*64..+63)
    int l16  = lane & 15;
    int quad = lane >> 4;
    int rswz = ((l16 >> 1) & 3) << 4;        // read-side slot XOR (bytes)

    const unsigned short* XpB = Xp + (size_t)b * XPIMG;
    const unsigned short* WbB = WbT + (size_t)b * F_ * K_;

    // staging: chunk c -> row = c>>2, col = c&3 (16B slots in 64B rows),
    // source chunk sc = col ^ ((row>>1)&3) = (t&3)^((t>>3)&3) for c=t
    // and c=t+512 alike. LDS dest linear = c*16B.
    int sc    = (t & 3) ^ ((t >> 3) & 3);
    int arow  = t >> 2;                       // 0..127
    int aoff  = (mt * 2 + (arow >> 6)) * XPROW + (arow & 63) * 128 + sc * 8;
    int boff0 = (t >> 2) * K_ + sc * 8;             // B rows 0..127
    int boff1 = (128 + (t >> 2)) * K_ + sc * 8;     // B rows 128..255

    f32x4 acc[4][4];
    #pragma unroll
    for (int mi = 0; mi < 4; ++mi)
        #pragma unroll
        for (int ni = 0; ni < 4; ++ni)
            acc[mi][ni] = (f32x4){0.f, 0.f, 0.f, 0.f};

    auto koffA = [&](int kt) {
        int khw = kt >> 2;
        int kh  = (khw * 11) >> 5;
        int kw  = khw - 3 * kh;
        return kh * XPROW + kw * 128 + (kt & 3) * 32;   // shorts
    };

    auto stage = [&](int buf, int kt) {
        int ka = koffA(kt);
        int kb = kt * 32;
        async16(XpB + aoff + ka,  &As[buf][t * 8]);
        async16(WbB + boff0 + kb, &Bs[buf][t * 8]);
        async16(WbB + boff1 + kb, &Bs[buf][(t + 512) * 8]);
    };

    // one iteration: read cur frags, optionally stage kt+2, 16 MFMA, gate
    auto iter = [&](const unsigned short* Ac, const unsigned short* Bc,
                    int stbuf, int stkt, int gate) {
        bf16x8 af[4], bf[4];
        #pragma unroll
        for (int mi = 0; mi < 4; ++mi) {
            int row = wm * 64 + mi * 16 + l16;
            af[mi] = *(const bf16x8*)((const char*)Ac +
                      ((row * 64 + quad * 16) ^ rswz));
        }
        #pragma unroll
        for (int ni = 0; ni < 4; ++ni) {
            int row = wn * 64 + ni * 16 + l16;
            bf[ni] = *(const bf16x8*)((const char*)Bc +
                      ((row * 64 + quad * 16) ^ rswz));
        }
        if (stbuf >= 0) stage(stbuf, stkt);
        __builtin_amdgcn_s_setprio(1);
        #pragma unroll
        for (int mi = 0; mi < 4; ++mi)
            #pragma unroll
            for (int ni = 0; ni < 4; ++ni)
                acc[mi][ni] = __builtin_amdgcn_mfma_f32_16x16x32_bf16(
                    af[mi], bf[ni], acc[mi][ni], 0, 0, 0);
        __builtin_amdgcn_s_setprio(0);
        if (gate == 3)      asm volatile("s_waitcnt vmcnt(3)" ::: "memory");
        else if (gate == 0) asm volatile("s_waitcnt vmcnt(0)" ::: "memory");
        if (gate >= 0) PHB;
    };

    // ---- prologue: stage tile0 -> buf0, tile1 -> buf1 ----
    stage(0, 0);
    stage(1, 1);
    asm volatile("s_waitcnt vmcnt(3)" ::: "memory");   // tile0 visible
    PHB;

    // ---- main loop: kt = 0..32 (11 x 3, compile-time buffer rotation) ----
    for (int k3 = 0; k3 < 11; ++k3) {
        int kt = k3 * 3;
        iter(As[0], Bs[0], 2, kt + 2, 3);
        iter(As[1], Bs[1], 0, kt + 3, 3);
        iter(As[2], Bs[2], 1, kt + 4, 3);
    }
    // kt=33: stage tile35 -> buf2; gate drains tile34
    iter(As[0], Bs[0], 2, 35, 3);
    // kt=34: no stage; drain tile35
    iter(As[1], Bs[1], -1, 0, 0);
    // kt=35: final, no gate/barrier
    iter(As[2], Bs[2], -1, 0, -1);

    // ---- epilogue: + bias*Berr, ReLU, store fp32 ----
    float mb[4];
    #pragma unroll
    for (int ni = 0; ni < 4; ++ni) {
        int f = wn * 64 + ni * 16 + l16;
        mb[ni] = bias[f] * Berr[b * F_ + f];
    }
    #pragma unroll
    for (int mi = 0; mi < 4; ++mi) {
        #pragma unroll
        for (int rr = 0; rr < 4; ++rr) {
            int mm = pm0 + wm * 64 + mi * 16 + quad * 4 + rr;
            float* orow = Out + ((size_t)b * M_ + mm) * F_ + wn * 64;
            #pragma unroll
            for (int ni = 0; ni < 4; ++ni) {
                float v = acc[mi][ni][rr] + mb[ni];
                orow[ni * 16 + l16] = fmaxf(v, 0.0f);
            }
        }
    }
}

// ---------------------------------------------------------------------------
// Mid-tier path (verified): fp32 X + in-loop cvt, 128x128 tile.
// ---------------------------------------------------------------------------
__global__ __launch_bounds__(256, 2)
void gemm_kernel_f32(const float* __restrict__ X,
                     const unsigned short* __restrict__ WbT,
                     const float* __restrict__ zpage,
                     const float* __restrict__ bias,
                     const float* __restrict__ Berr,
                     float* __restrict__ Out) {
    __shared__ unsigned short As[128 * 32];
    __shared__ unsigned short Bs[128 * 32];

    int bid = blockIdx.x;
    int g   = (bid & 7) | ((bid >> 8) << 3);
    int mt  = (bid >> 3) & 31;
    int b   = g >> 1;
    int nt  = g & 1;
    int pm0 = mt * 128;

    int t    = threadIdx.x;
    int lane = t & 63;
    int wv   = t >> 6;
    int wm   = wv >> 1;
    int wn   = wv & 1;
    int l16  = lane & 15;
    int quad = lane >> 4;

    int ml   = t >> 1;
    int half = t & 1;
    int m    = pm0 + ml;
    int hb   = m >> 6;
    int wwv  = m & 63;
    const float* Abase = X + (((size_t)b * 64 + hb - 1) * 64 + (wwv - 1)) * 128
                           + half * 16;
    unsigned vm = 0;
    #pragma unroll
    for (int khw = 0; khw < 9; ++khw) {
        int kh = (khw * 11) >> 5;
        int kw = khw - kh * 3;
        bool ok = ((unsigned)(hb + kh - 1) < 64u) && ((unsigned)(wwv + kw - 1) < 64u);
        vm |= (unsigned)ok << khw;
    }
    int ldsA = ml * 32 + half * 16;

    const unsigned short* wb = WbT + ((size_t)(b * F_ + nt * 128)) * K_;
    const unsigned short* Bbase[2];
    int ldsB[2];
    #pragma unroll
    for (int cc = 0; cc < 2; ++cc) {
        int c   = t + cc * 256;
        int nl  = c >> 2;
        int off = c & 3;
        Bbase[cc] = wb + (size_t)nl * K_ + off * 8;
        ldsB[cc]  = c * 8;
    }

    f32x4 acc[4][4];
    #pragma unroll
    for (int mi = 0; mi < 4; ++mi)
        #pragma unroll
        for (int ni = 0; ni < 4; ++ni)
            acc[mi][ni] = (f32x4){0.f, 0.f, 0.f, 0.f};

    f32x4 pr0, pr1, pr2, pr3;
    {
        const float* p = (vm & 1) ? Abase : zpage;
        pr0 = *(const f32x4*)(p);
        pr1 = *(const f32x4*)(p + 4);
        pr2 = *(const f32x4*)(p + 8);
        pr3 = *(const f32x4*)(p + 12);
    }

    for (int kt = 0; kt < 36; ++kt) {
        uint4 lo, hi;
        lo.x = pkbf(pr0[0], pr0[1]);  lo.y = pkbf(pr0[2], pr0[3]);
        lo.z = pkbf(pr1[0], pr1[1]);  lo.w = pkbf(pr1[2], pr1[3]);
        hi.x = pkbf(pr2[0], pr2[1]);  hi.y = pkbf(pr2[2], pr2[3]);
        hi.z = pkbf(pr3[0], pr3[1]);  hi.w = pkbf(pr3[2], pr3[3]);

        if (kt) __syncthreads();
        *(uint4*)&As[ldsA]     = lo;
        *(uint4*)&As[ldsA + 8] = hi;
        #pragma unroll
        for (int cc = 0; cc < 2; ++cc)
            async16(Bbase[cc] + kt * 32, &Bs[ldsB[cc]]);
        __syncthreads();

        if (kt < 35) {
            int ktn  = kt + 1;
            int khw  = ktn >> 2;
            int kh   = (khw * 11) >> 5;
            int kw   = khw - kh * 3;
            int koff = kh * 8192 + kw * 128 + ((ktn & 3) << 5);
            const float* p = ((vm >> khw) & 1) ? Abase + koff : zpage;
            pr0 = *(const f32x4*)(p);
            pr1 = *(const f32x4*)(p + 4);
            pr2 = *(const f32x4*)(p + 8);
            pr3 = *(const f32x4*)(p + 12);
        }

        bf16x8 af[4], bf[4];
        #pragma unroll
        for (int i = 0; i < 4; ++i) {
            af[i] = *(const bf16x8*)&As[(wm * 64 + i * 16 + l16) * 32 + quad * 8];
            bf[i] = *(const bf16x8*)&Bs[(wn * 64 + i * 16 + l16) * 32 + quad * 8];
        }
        #pragma unroll
        for (int mi = 0; mi < 4; ++mi)
            #pragma unroll
            for (int ni = 0; ni < 4; ++ni)
                acc[mi][ni] = __builtin_amdgcn_mfma_f32_16x16x32_bf16(
                    af[mi], bf[ni], acc[mi][ni], 0, 0, 0);
    }

    float mb[4];
    #pragma unroll
    for (int ni = 0; ni < 4; ++ni) {
        int f = nt * 128 + wn * 64 + ni * 16 + l16;
        mb[ni] = bias[f] * Berr[b * F_ + f];
    }
    #pragma unroll
    for (int mi = 0; mi < 4; ++mi) {
        #pragma unroll
        for (int rr = 0; rr < 4; ++rr) {
            int mm = pm0 + wm * 64 + mi * 16 + quad * 4 + rr;
            float* orow = Out + ((size_t)b * M_ + mm) * F_ + nt * 128 + wn * 64;
            #pragma unroll
            for (int ni = 0; ni < 4; ++ni) {
                float v = acc[mi][ni][rr] + mb[ni];
                orow[ni * 16 + l16] = fmaxf(v, 0.0f);
            }
        }
    }
}

// ---------------------------------------------------------------------------
// Zero-workspace fallback: direct conv (slow but correct), ws < 19MB only.
// ---------------------------------------------------------------------------
__global__ __launch_bounds__(256)
void fallback_kernel(const float* __restrict__ X, const float* __restrict__ W,
                     const float* __restrict__ bias, const float* __restrict__ Werr,
                     const float* __restrict__ Berr, float* __restrict__ Out) {
    __shared__ float Xs[3 * 66 * 128];
    int bid = blockIdx.x;
    int b = bid >> 6;
    int h = bid & 63;
    int t = threadIdx.x;
    int f = t;

    for (int e = t; e < 3 * 66 * 128; e += 256) {
        int kh  = e / (66 * 128);
        int rem = e - kh * 66 * 128;
        int w66 = rem >> 7;
        int c   = rem & 127;
        int hh = h + kh - 1, ww = w66 - 1;
        float v = 0.f;
        if (hh >= 0 && hh < 64 && ww >= 0 && ww < 64)
            v = X[(((size_t)b * 64 + hh) * 64 + ww) * 128 + c];
        Xs[e] = v;
    }
    __syncthreads();

    float acc[64];
    #pragma unroll
    for (int w = 0; w < 64; ++w) acc[w] = 0.f;

    for (int kk = 0; kk < 9; ++kk) {
        int kh = (kk * 11) >> 5;
        int kw = kk - kh * 3;
        for (int c = 0; c < 128; ++c) {
            size_t wi = ((size_t)kk * 128 + c) * 256 + f;
            float wvv = W[wi] * Werr[(size_t)b * (K_ * F_) + wi];
            const float* xr = &Xs[(kh * 66 + kw) * 128 + c];
            #pragma unroll
            for (int w = 0; w < 64; ++w)
                acc[w] = fmaf(xr[w * 128], wvv, acc[w]);
        }
    }
    float mb = bias[f] * Berr[b * 256 + f];
    for (int w = 0; w < 64; ++w)
        Out[(((size_t)b * 64 + h) * 64 + w) * 256 + f] = fmaxf(acc[w] + mb, 0.f);
}

// ---------------------------------------------------------------------------
extern "C" void kernel_launch(void* const* d_in, const int* in_sizes, int n_in,
                              void* d_out, int out_size, void* d_ws, size_t ws_size,
                              hipStream_t stream) {
    const float* X    = (const float*)d_in[0];
    const float* W    = (const float*)d_in[1];
    const float* bias = (const float*)d_in[2];
    const float* Werr = (const float*)d_in[3];
    const float* Berr = (const float*)d_in[4];
    float* Out = (float*)d_out;

    if (ws_size >= FULL_WS) {
        unsigned short* WbT = (unsigned short*)d_ws;
        unsigned short* Xp  = (unsigned short*)((char*)d_ws + WBT_BYTES);
        unsigned int*   zpg = (unsigned int*)((char*)d_ws + WBT_BYTES + XP_BYTES);
        prep_kernel<<<4608 + 8712, 256, 0, stream>>>(W, Werr, X, WbT, Xp, zpg);
        gemm128_kernel<<<1024, 512, 0, stream>>>(Xp, WbT, bias, Berr, Out);
    } else if (ws_size >= WBT_BYTES + 256) {
        unsigned short* WbT  = (unsigned short*)d_ws;
        unsigned int*   zpg  = (unsigned int*)((char*)d_ws + ZPAGE_OFF);
        wbt_kernel<<<B_ * 36 * 4, 256, 0, stream>>>(W, Werr, WbT, zpg);
        gemm_kernel_f32<<<B_ * 32 * 2, 256, 0, stream>>>(X, WbT, (const float*)zpg,
                                                         bias, Berr, Out);
    } else {
        fallback_kernel<<<B_ * 64, 256, 0, stream>>>(X, W, bias, Werr, Berr, Out);
    }
}

// Round 7
// 289.398 us; speedup vs baseline: 1.0405x; 1.0266x over previous
//
#include <hip/hip_runtime.h>

// Problem constants
#define B_   32
#define H_   64
#define W_   64
#define CIN  128
#define F_   256
#define K_   1152          // 3*3*128
#define M_   4096          // H*W per batch

// Padded bf16 image: [B][66][66][128]
#define HP_   66
#define XPROW (66*128)          // 8448
#define XPIMG (66*66*128)       // 557568
#define XP_ELEMS ((size_t)B_ * XPIMG)
#define XP_BYTES (XP_ELEMS * 2)                 // 35,684,352

#define WBT_BYTES ((size_t)B_ * F_ * K_ * 2)    // 18,874,368
#define FULL_WS   (WBT_BYTES + XP_BYTES + 256)
#define ZPAGE_OFF WBT_BYTES                     // mid-tier zero page

// gemm256 geometry
#define BM_ 256
#define BK_ 64

// prep geometry: wbt 64k x 64f tiles, xp 4 chunks/thread, 512 thr
#define WBT_BLOCKS (32 * 18 * 4)        // 2304
#define XP_BLOCKS  1089                 // 1089*2048 == 2,230,272 chunks
#define PREP_GRID  (WBT_BLOCKS + XP_BLOCKS)

typedef __attribute__((ext_vector_type(8))) short bf16x8;
typedef __attribute__((ext_vector_type(4))) float f32x4;

// pack two floats -> two bf16 (round-to-nearest) in one v_perm
__device__ __forceinline__ unsigned pkbf(float a, float b) {
    unsigned ua = __builtin_bit_cast(unsigned, a) + 0x8000u;
    unsigned ub = __builtin_bit_cast(unsigned, b) + 0x8000u;
    return __builtin_amdgcn_perm(ub, ua, 0x07060302u);
}

__device__ __forceinline__ void async16(const void* g, void* l) {
    __builtin_amdgcn_global_load_lds(
        (const __attribute__((address_space(1))) unsigned int*)g,
        (__attribute__((address_space(3))) unsigned int*)l, 16, 0, 0);
}

// ---------------------------------------------------------------------------
// prep v2 (512 thr): blocks [0,2304) do WbT in 64k x 64f tiles; blocks
// [2304,3393) do Xp with 4 chunks/thread.
//   WbT[b][f][k] = bf16( W[k][f] * Werr[b][k][f] )
//     - loads: f32x4 along f (coalesced)
//     - LDS transpose, stride 65 (bank = (r+fl)%32 -> 2-way, free)
//     - stores: 8 threads per f-row x 16B = 128B full-line coalesced
//   Xp = bf16 zero-padded X image [32][66][66][128], 16B store per chunk.
// ---------------------------------------------------------------------------
__global__ __launch_bounds__(512)
void prep_kernel(const float* __restrict__ W,
                 const float* __restrict__ Werr,
                 const float* __restrict__ X,
                 unsigned short* __restrict__ WbT,
                 unsigned short* __restrict__ Xp,
                 unsigned int* __restrict__ zpage) {
    int bid = blockIdx.x;
    int t   = threadIdx.x;

    if (bid < WBT_BLOCKS) {
        // ---- WbT body: 64k x 64f tile ----
        __shared__ float tile[64 * 65];   // 16.6KB
        int ft   = bid & 3;
        int rest = bid >> 2;
        int kt2  = rest % 18;
        int b    = rest / 18;
        int k0 = kt2 * 64;
        int f0 = ft * 64;

        if (bid == 0 && t < 64) zpage[t] = 0u;   // mid-tier zero page

        #pragma unroll
        for (int i = 0; i < 2; ++i) {
            int c   = i * 512 + t;        // 0..1023
            int kl  = c >> 4;             // 0..63
            int fl4 = c & 15;             // f offset = fl4*4
            size_t src = (size_t)(k0 + kl) * F_ + f0 + fl4 * 4;
            f32x4 w4 = *(const f32x4*)&W[src];
            f32x4 e4 = *(const f32x4*)&Werr[(size_t)b * (K_ * F_) + src];
            f32x4 v  = w4 * e4;
            #pragma unroll
            for (int u = 0; u < 4; ++u)
                tile[kl * 65 + fl4 * 4 + u] = v[u];
        }
        __syncthreads();
        {
            int fl = t >> 3;              // 0..63 (f-row)
            int ku = t & 7;               // 0..7  (k unit of 8)
            unsigned pk[4];
            #pragma unroll
            for (int j2 = 0; j2 < 4; ++j2) {
                float x0 = tile[(ku * 8 + j2 * 2 + 0) * 65 + fl];
                float x1 = tile[(ku * 8 + j2 * 2 + 1) * 65 + fl];
                pk[j2] = pkbf(x0, x1);
            }
            // 8 threads (ku=0..7) per f-row write 128B contiguous
            size_t dst = ((size_t)(b * F_ + f0 + fl)) * K_ + k0 + ku * 8;
            *(uint4*)&WbT[dst] = make_uint4(pk[0], pk[1], pk[2], pk[3]);
        }
    } else {
        // ---- Xp body: 4 chunks per thread ----
        int base = (bid - WBT_BLOCKS) * 2048;
        #pragma unroll
        for (int i = 0; i < 4; ++i) {
            int e = base + i * 512 + t;   // chunk id, < 2,230,272
            int c16  = e & 15;            // channel block of 8
            int pos  = e >> 4;            // (b*66 + hp)*66 + wp
            int wp   = pos % 66;
            int rest = pos / 66;
            int hp   = rest % 66;
            int b    = rest / 66;
            uint4 out;
            if (hp >= 1 && hp <= 64 && wp >= 1 && wp <= 64) {
                const float* src = X + (((size_t)b * 64 + (hp - 1)) * 64 + (wp - 1)) * 128
                                     + c16 * 8;
                f32x4 a = *(const f32x4*)src;
                f32x4 c = *(const f32x4*)(src + 4);
                out.x = pkbf(a[0], a[1]);  out.y = pkbf(a[2], a[3]);
                out.z = pkbf(c[0], c[1]);  out.w = pkbf(c[2], c[3]);
            } else {
                out = make_uint4(0u, 0u, 0u, 0u);
            }
            *(uint4*)&Xp[(size_t)e * 8] = out;
        }
    }
}

// Standalone WbT kernel for the mid-tier path (no Xp space in ws).
__global__ void wbt_kernel(const float* __restrict__ W,
                           const float* __restrict__ Werr,
                           unsigned short* __restrict__ WbT,
                           unsigned int* __restrict__ zpage) {
    __shared__ float tile[32 * 68];
    int bid = blockIdx.x;
    int ft   = bid & 3;
    int rest = bid >> 2;
    int kt   = rest % 36;
    int b    = rest / 36;
    int k0 = kt * 32;
    int f0 = ft * 64;
    int t  = threadIdx.x;

    if (bid == 0 && t < 64) zpage[t] = 0u;

    #pragma unroll
    for (int i = 0; i < 2; ++i) {
        int c   = i * 256 + t;
        int kl  = c >> 4;
        int fl4 = c & 15;
        size_t src = (size_t)(k0 + kl) * F_ + f0 + fl4 * 4;
        f32x4 w4 = *(const f32x4*)&W[src];
        f32x4 e4 = *(const f32x4*)&Werr[(size_t)b * (K_ * F_) + src];
        f32x4 v  = w4 * e4;
        *(f32x4*)&tile[kl * 68 + fl4 * 4] = v;
    }
    __syncthreads();
    {
        int c  = t;
        int fl = c >> 2;
        int ku = c & 3;
        unsigned pk[4];
        #pragma unroll
        for (int j2 = 0; j2 < 4; ++j2) {
            float x0 = tile[(ku * 8 + j2 * 2 + 0) * 68 + fl];
            float x1 = tile[(ku * 8 + j2 * 2 + 1) * 68 + fl];
            pk[j2] = pkbf(x0, x1);
        }
        size_t dst = ((size_t)(b * F_ + f0 + fl)) * K_ + k0 + ku * 8;
        *(uint4*)&WbT[dst] = make_uint4(pk[0], pk[1], pk[2], pk[3]);
    }
}

// ---------------------------------------------------------------------------
// gemm256 (R4-exact, measured 85.9us / MfmaUtil 37.5): 256x256 tile, BK=64,
// 8 waves, 128KB LDS double-buffered, TWO counted-vmcnt gates per K-tile.
//   entry state: cur{B0-3,A0,A2} visible; cur{A1,A3} in flight (2 outst.)
//   part1: read khalf0/qm0 frags; issue B0-3(nxt); 16 MFMA
//   G2: vmcnt(4) -> drains cur{A1,A3}; barrier
//   part2: read rest of cur; issue A0,A2,A1,A3(nxt); 48 MFMA
//   G1: vmcnt(2) -> drains nxt{B0-3,A0,A2}; leaves nxt{A1,A3}; barrier
// T2 swizzle both-sides (0 bank conflicts, verified); T5 setprio.
// grid = 512, XCD-swizzled.
// ---------------------------------------------------------------------------
__global__ __launch_bounds__(512, 2)
void gemm256_kernel(const unsigned short* __restrict__ Xp,
                    const unsigned short* __restrict__ WbT,
                    const float* __restrict__ bias,
                    const float* __restrict__ Berr,
                    float* __restrict__ Out) {
    __shared__ unsigned short As[2][BM_ * BK_];   // 2 x 32KB
    __shared__ unsigned short Bs[2][BM_ * BK_];   // 2 x 32KB

    int bid = blockIdx.x;
    int g   = (bid & 7) * 64 + (bid >> 3);   // bijective, 512 % 8 == 0
    int b   = g >> 4;                        // 0..31
    int mt  = g & 15;                        // 0..15
    int pm0 = mt * 256;

    int t    = threadIdx.x;
    int lane = t & 63;
    int wv   = t >> 6;
    int wm   = wv >> 2;       // 0..1
    int wn   = wv & 3;        // 0..3
    int l16  = lane & 15;
    int quad = lane >> 4;
    int swz  = (l16 & 7) << 4;   // byte-XOR for ds_read (bits 4-6)

    const unsigned short* XpB = Xp + (size_t)b * XPIMG;
    const unsigned short* WbB = WbT + (size_t)b * F_ * K_;

    int tr   = t >> 3;                    // 0..63 row within unit
    int sc   = (t & 7) ^ (tr & 7);        // inverse-swizzled source chunk
    int aoff = tr * 128 + sc * 8;         // shorts within an A unit row-block
    int boff = tr * K_ + sc * 8;          // shorts within a B unit row-block
    int mbase = mt * 4;                   // A unit h-base (pm0/64)
    int ldof = t * 8;                     // shorts, per-unit LDS offset

    f32x4 acc[8][4];
    #pragma unroll
    for (int mi = 0; mi < 8; ++mi)
        #pragma unroll
        for (int ni = 0; ni < 4; ++ni)
            acc[mi][ni] = (f32x4){0.f, 0.f, 0.f, 0.f};

    auto stageA = [&](int bs, int ru, int ko) {
        async16(XpB + (size_t)(mbase + ru) * XPROW + aoff + ko,
                &As[bs][ru * 4096 + ldof]);
    };
    auto stageB = [&](int bs, int ru, int ko) {
        async16(WbB + (size_t)ru * (64 * K_) + boff + ko,
                &Bs[bs][ru * 4096 + ldof]);
    };

    // ---- prologue: stage K-tile 0 into buffer 0, ordered for the gates ----
    stageB(0, 0, 0); stageB(0, 1, 0); stageB(0, 2, 0); stageB(0, 3, 0);
    stageA(0, 0, 0); stageA(0, 2, 0); stageA(0, 1, 0); stageA(0, 3, 0);
    asm volatile("s_waitcnt vmcnt(2)" ::: "memory");   // B-all + A{0,2} landed
    __builtin_amdgcn_s_barrier();
    __builtin_amdgcn_sched_barrier(0);

    for (int kt = 0; kt < 18; ++kt) {
        const int cur = kt & 1;
        const int nxt = cur ^ 1;
        const unsigned short* Ac = As[cur];
        const unsigned short* Bc = Bs[cur];
        const bool pf = (kt < 17);

        // uniform source offsets for K-tile kt+1
        int ktn  = kt + 1;
        int khwN = ktn >> 1;
        int khN  = (khwN * 11) >> 5;
        int kwN  = khwN - khN * 3;
        int koA  = khN * XPROW + kwN * 128 + (ktn & 1) * 64;  // shorts
        int koB  = ktn * 64;                                   // shorts

        // ================= part 1: khalf0, qm0 (16 MFMA) =================
        bf16x8 b0[4], a0[4];
        #pragma unroll
        for (int ni = 0; ni < 4; ++ni) {
            int row = wn * 64 + ni * 16 + l16;
            b0[ni] = *(const bf16x8*)((const char*)Bc + ((row * 128 + quad * 16) ^ swz));
        }
        #pragma unroll
        for (int mi = 0; mi < 4; ++mi) {
            int row = wm * 128 + mi * 16 + l16;
            a0[mi] = *(const bf16x8*)((const char*)Ac + ((row * 128 + quad * 16) ^ swz));
        }
        if (pf) {
            stageB(nxt, 0, koB); stageB(nxt, 1, koB);
            stageB(nxt, 2, koB); stageB(nxt, 3, koB);
        }
        __builtin_amdgcn_s_setprio(1);
        #pragma unroll
        for (int mi = 0; mi < 4; ++mi)
            #pragma unroll
            for (int ni = 0; ni < 4; ++ni)
                acc[mi][ni] = __builtin_amdgcn_mfma_f32_16x16x32_bf16(
                    a0[mi], b0[ni], acc[mi][ni], 0, 0, 0);
        __builtin_amdgcn_s_setprio(0);

        // ---- gate G2: cur{A1,A3} visible (issued a full K-tile ago) ----
        if (pf) asm volatile("s_waitcnt vmcnt(4)" ::: "memory");
        else    asm volatile("s_waitcnt vmcnt(0)" ::: "memory");
        __builtin_amdgcn_s_barrier();
        __builtin_amdgcn_sched_barrier(0);

        // ================= part 2a: khalf0, qm1 (16 MFMA) =================
        bf16x8 a1[4];
        #pragma unroll
        for (int mi = 0; mi < 4; ++mi) {
            int row = wm * 128 + 64 + mi * 16 + l16;
            a1[mi] = *(const bf16x8*)((const char*)Ac + ((row * 128 + quad * 16) ^ swz));
        }
        if (pf) {
            stageA(nxt, 0, koA); stageA(nxt, 2, koA);
            stageA(nxt, 1, koA); stageA(nxt, 3, koA);
        }
        __builtin_amdgcn_s_setprio(1);
        #pragma unroll
        for (int mi = 0; mi < 4; ++mi)
            #pragma unroll
            for (int ni = 0; ni < 4; ++ni)
                acc[4 + mi][ni] = __builtin_amdgcn_mfma_f32_16x16x32_bf16(
                    a1[mi], b0[ni], acc[4 + mi][ni], 0, 0, 0);
        __builtin_amdgcn_s_setprio(0);

        // ================= part 2b: khalf1, qm0+qm1 (32 MFMA) =================
        bf16x8 b1[4], a2[4], a3[4];
        #pragma unroll
        for (int ni = 0; ni < 4; ++ni) {
            int row = wn * 64 + ni * 16 + l16;
            b1[ni] = *(const bf16x8*)((const char*)Bc + ((row * 128 + quad * 16 + 64) ^ swz));
        }
        #pragma unroll
        for (int mi = 0; mi < 4; ++mi) {
            int row = wm * 128 + mi * 16 + l16;
            a2[mi] = *(const bf16x8*)((const char*)Ac + ((row * 128 + quad * 16 + 64) ^ swz));
        }
        #pragma unroll
        for (int mi = 0; mi < 4; ++mi) {
            int row = wm * 128 + 64 + mi * 16 + l16;
            a3[mi] = *(const bf16x8*)((const char*)Ac + ((row * 128 + quad * 16 + 64) ^ swz));
        }
        __builtin_amdgcn_s_setprio(1);
        #pragma unroll
        for (int mi = 0; mi < 4; ++mi)
            #pragma unroll
            for (int ni = 0; ni < 4; ++ni)
                acc[mi][ni] = __builtin_amdgcn_mfma_f32_16x16x32_bf16(
                    a2[mi], b1[ni], acc[mi][ni], 0, 0, 0);
        #pragma unroll
        for (int mi = 0; mi < 4; ++mi)
            #pragma unroll
            for (int ni = 0; ni < 4; ++ni)
                acc[4 + mi][ni] = __builtin_amdgcn_mfma_f32_16x16x32_bf16(
                    a3[mi], b1[ni], acc[4 + mi][ni], 0, 0, 0);
        __builtin_amdgcn_s_setprio(0);

        // ---- gate G1: nxt{B0-3,A0,A2} visible; nxt{A1,A3} stay in flight ----
        if (pf) {
            asm volatile("s_waitcnt vmcnt(2)" ::: "memory");
            __builtin_amdgcn_s_barrier();
            __builtin_amdgcn_sched_barrier(0);
        }
    }

    // ---- epilogue: + bias*Berr, ReLU, store fp32 ----
    float mb[4];
    #pragma unroll
    for (int ni = 0; ni < 4; ++ni) {
        int f = wn * 64 + ni * 16 + l16;
        mb[ni] = bias[f] * Berr[b * F_ + f];
    }
    #pragma unroll
    for (int mi = 0; mi < 8; ++mi) {
        #pragma unroll
        for (int rr = 0; rr < 4; ++rr) {
            int mm = pm0 + wm * 128 + mi * 16 + quad * 4 + rr;
            float* orow = Out + ((size_t)b * M_ + mm) * F_ + wn * 64;
            #pragma unroll
            for (int ni = 0; ni < 4; ++ni) {
                float v = acc[mi][ni][rr] + mb[ni];
                orow[ni * 16 + l16] = fmaxf(v, 0.0f);
            }
        }
    }
}

// ---------------------------------------------------------------------------
// Mid-tier path (verified): fp32 X + in-loop cvt, 128x128 tile.
// ---------------------------------------------------------------------------
__global__ __launch_bounds__(256, 2)
void gemm_kernel_f32(const float* __restrict__ X,
                     const unsigned short* __restrict__ WbT,
                     const float* __restrict__ zpage,
                     const float* __restrict__ bias,
                     const float* __restrict__ Berr,
                     float* __restrict__ Out) {
    __shared__ unsigned short As[128 * 32];
    __shared__ unsigned short Bs[128 * 32];

    int bid = blockIdx.x;
    int g   = (bid & 7) | ((bid >> 8) << 3);
    int mt  = (bid >> 3) & 31;
    int b   = g >> 1;
    int nt  = g & 1;
    int pm0 = mt * 128;

    int t    = threadIdx.x;
    int lane = t & 63;
    int wv   = t >> 6;
    int wm   = wv >> 1;
    int wn   = wv & 1;
    int l16  = lane & 15;
    int quad = lane >> 4;

    int ml   = t >> 1;
    int half = t & 1;
    int m    = pm0 + ml;
    int hb   = m >> 6;
    int wwv  = m & 63;
    const float* Abase = X + (((size_t)b * 64 + hb - 1) * 64 + (wwv - 1)) * 128
                           + half * 16;
    unsigned vm = 0;
    #pragma unroll
    for (int khw = 0; khw < 9; ++khw) {
        int kh = (khw * 11) >> 5;
        int kw = khw - kh * 3;
        bool ok = ((unsigned)(hb + kh - 1) < 64u) && ((unsigned)(wwv + kw - 1) < 64u);
        vm |= (unsigned)ok << khw;
    }
    int ldsA = ml * 32 + half * 16;

    const unsigned short* wb = WbT + ((size_t)(b * F_ + nt * 128)) * K_;
    const unsigned short* Bbase[2];
    int ldsB[2];
    #pragma unroll
    for (int cc = 0; cc < 2; ++cc) {
        int c   = t + cc * 256;
        int nl  = c >> 2;
        int off = c & 3;
        Bbase[cc] = wb + (size_t)nl * K_ + off * 8;
        ldsB[cc]  = c * 8;
    }

    f32x4 acc[4][4];
    #pragma unroll
    for (int mi = 0; mi < 4; ++mi)
        #pragma unroll
        for (int ni = 0; ni < 4; ++ni)
            acc[mi][ni] = (f32x4){0.f, 0.f, 0.f, 0.f};

    f32x4 pr0, pr1, pr2, pr3;
    {
        const float* p = (vm & 1) ? Abase : zpage;
        pr0 = *(const f32x4*)(p);
        pr1 = *(const f32x4*)(p + 4);
        pr2 = *(const f32x4*)(p + 8);
        pr3 = *(const f32x4*)(p + 12);
    }

    for (int kt = 0; kt < 36; ++kt) {
        uint4 lo, hi;
        lo.x = pkbf(pr0[0], pr0[1]);  lo.y = pkbf(pr0[2], pr0[3]);
        lo.z = pkbf(pr1[0], pr1[1]);  lo.w = pkbf(pr1[2], pr1[3]);
        hi.x = pkbf(pr2[0], pr2[1]);  hi.y = pkbf(pr2[2], pr2[3]);
        hi.z = pkbf(pr3[0], pr3[1]);  hi.w = pkbf(pr3[2], pr3[3]);

        if (kt) __syncthreads();
        *(uint4*)&As[ldsA]     = lo;
        *(uint4*)&As[ldsA + 8] = hi;
        #pragma unroll
        for (int cc = 0; cc < 2; ++cc)
            async16(Bbase[cc] + kt * 32, &Bs[ldsB[cc]]);
        __syncthreads();

        if (kt < 35) {
            int ktn  = kt + 1;
            int khw  = ktn >> 2;
            int kh   = (khw * 11) >> 5;
            int kw   = khw - kh * 3;
            int koff = kh * 8192 + kw * 128 + ((ktn & 3) << 5);
            const float* p = ((vm >> khw) & 1) ? Abase + koff : zpage;
            pr0 = *(const f32x4*)(p);
            pr1 = *(const f32x4*)(p + 4);
            pr2 = *(const f32x4*)(p + 8);
            pr3 = *(const f32x4*)(p + 12);
        }

        bf16x8 af[4], bf[4];
        #pragma unroll
        for (int i = 0; i < 4; ++i) {
            af[i] = *(const bf16x8*)&As[(wm * 64 + i * 16 + l16) * 32 + quad * 8];
            bf[i] = *(const bf16x8*)&Bs[(wn * 64 + i * 16 + l16) * 32 + quad * 8];
        }
        #pragma unroll
        for (int mi = 0; mi < 4; ++mi)
            #pragma unroll
            for (int ni = 0; ni < 4; ++ni)
                acc[mi][ni] = __builtin_amdgcn_mfma_f32_16x16x32_bf16(
                    af[mi], bf[ni], acc[mi][ni], 0, 0, 0);
    }

    float mb[4];
    #pragma unroll
    for (int ni = 0; ni < 4; ++ni) {
        int f = nt * 128 + wn * 64 + ni * 16 + l16;
        mb[ni] = bias[f] * Berr[b * F_ + f];
    }
    #pragma unroll
    for (int mi = 0; mi < 4; ++mi) {
        #pragma unroll
        for (int rr = 0; rr < 4; ++rr) {
            int mm = pm0 + wm * 64 + mi * 16 + quad * 4 + rr;
            float* orow = Out + ((size_t)b * M_ + mm) * F_ + nt * 128 + wn * 64;
            #pragma unroll
            for (int ni = 0; ni < 4; ++ni) {
                float v = acc[mi][ni][rr] + mb[ni];
                orow[ni * 16 + l16] = fmaxf(v, 0.0f);
            }
        }
    }
}

// ---------------------------------------------------------------------------
// Zero-workspace fallback: direct conv (slow but correct), ws < 19MB only.
// ---------------------------------------------------------------------------
__global__ __launch_bounds__(256)
void fallback_kernel(const float* __restrict__ X, const float* __restrict__ W,
                     const float* __restrict__ bias, const float* __restrict__ Werr,
                     const float* __restrict__ Berr, float* __restrict__ Out) {
    __shared__ float Xs[3 * 66 * 128];
    int bid = blockIdx.x;
    int b = bid >> 6;
    int h = bid & 63;
    int t = threadIdx.x;
    int f = t;

    for (int e = t; e < 3 * 66 * 128; e += 256) {
        int kh  = e / (66 * 128);
        int rem = e - kh * 66 * 128;
        int w66 = rem >> 7;
        int c   = rem & 127;
        int hh = h + kh - 1, ww = w66 - 1;
        float v = 0.f;
        if (hh >= 0 && hh < 64 && ww >= 0 && ww < 64)
            v = X[(((size_t)b * 64 + hh) * 64 + ww) * 128 + c];
        Xs[e] = v;
    }
    __syncthreads();

    float acc[64];
    #pragma unroll
    for (int w = 0; w < 64; ++w) acc[w] = 0.f;

    for (int kk = 0; kk < 9; ++kk) {
        int kh = (kk * 11) >> 5;
        int kw = kk - kh * 3;
        for (int c = 0; c < 128; ++c) {
            size_t wi = ((size_t)kk * 128 + c) * 256 + f;
            float wvv = W[wi] * Werr[(size_t)b * (K_ * F_) + wi];
            const float* xr = &Xs[(kh * 66 + kw) * 128 + c];
            #pragma unroll
            for (int w = 0; w < 64; ++w)
                acc[w] = fmaf(xr[w * 128], wvv, acc[w]);
        }
    }
    float mb = bias[f] * Berr[b * 256 + f];
    for (int w = 0; w < 64; ++w)
        Out[(((size_t)b * 64 + h) * 64 + w) * 256 + f] = fmaxf(acc[w] + mb, 0.f);
}

// ---------------------------------------------------------------------------
extern "C" void kernel_launch(void* const* d_in, const int* in_sizes, int n_in,
                              void* d_out, int out_size, void* d_ws, size_t ws_size,
                              hipStream_t stream) {
    const float* X    = (const float*)d_in[0];
    const float* W    = (const float*)d_in[1];
    const float* bias = (const float*)d_in[2];
    const float* Werr = (const float*)d_in[3];
    const float* Berr = (const float*)d_in[4];
    float* Out = (float*)d_out;

    if (ws_size >= FULL_WS) {
        unsigned short* WbT = (unsigned short*)d_ws;
        unsigned short* Xp  = (unsigned short*)((char*)d_ws + WBT_BYTES);
        unsigned int*   zpg = (unsigned int*)((char*)d_ws + WBT_BYTES + XP_BYTES);
        prep_kernel<<<PREP_GRID, 512, 0, stream>>>(W, Werr, X, WbT, Xp, zpg);
        gemm256_kernel<<<512, 512, 0, stream>>>(Xp, WbT, bias, Berr, Out);
    } else if (ws_size >= WBT_BYTES + 256) {
        unsigned short* WbT  = (unsigned short*)d_ws;
        unsigned int*   zpg  = (unsigned int*)((char*)d_ws + ZPAGE_OFF);
        wbt_kernel<<<B_ * 36 * 4, 256, 0, stream>>>(W, Werr, WbT, zpg);
        gemm_kernel_f32<<<B_ * 32 * 2, 256, 0, stream>>>(X, WbT, (const float*)zpg,
                                                         bias, Berr, Out);
    } else {
        fallback_kernel<<<B_ * 64, 256, 0, stream>>>(X, W, bias, Werr, Berr, Out);
    }
}